// Round 15
// baseline (401.782 us; speedup 1.0000x reference)
//
#include <hip/hip_runtime.h>

#define NN 50000
#define EE 800000
#define TT 12
#define BB 2

// ws layout (4B units):
//  [0, 50048)            dinv
//  [50048, 2450048)      AX[b][n][t][f]  (BB*NN*TT*2 floats)
//  [2450048, 2454144)    P folded params: per gate g at g*1120:
//          [0:32) WF0, [32:64) WF1, [64:96) cF, [96+32k+j) LB[k][j]
//        probs at [3360:3372)
//  [2454144, 2504192)    cnt (int)
//  [2504192, 2554240)    off (int)
//  [2554240, 2604288)    cur (int)
//  [2604288, 2604416)    bsum (int)
// CSR payload lives in d_out (fully overwritten by k_recur at the end):
//  d_out[0..800000)        esrc (int)
//  d_out[800000..1600000)  ewgt (float)
#define OFF_AX   50048
#define OFF_P    2450048
#define OFF_CNT  2454144
#define OFF_OFF  2504192
#define OFF_CUR  2554240
#define OFF_BSUM 2604288
#define NB_SCAN  98  // ceil(50000/512)
#define NPAIR    (BB * NN / 2)
#define NBLK_REC 2048

__device__ __forceinline__ float fsig(float x) {
    x = fminf(fmaxf(x, -30.f), 30.f);
    return __builtin_amdgcn_rcpf(1.f + __expf(-x));
}
__device__ __forceinline__ float ftanh(float x) {
    x = fminf(fmaxf(x, -15.f), 15.f);
    float e = __expf(-2.f * x);
    return (1.f - e) * __builtin_amdgcn_rcpf(1.f + e);
}

__global__ void k_zero(int* __restrict__ cnt) {
    int i = blockIdx.x * 256 + threadIdx.x;
    if (i < NN) cnt[i] = 0;
}

__global__ void k_count(const int* __restrict__ idx, int* __restrict__ cnt) {
    int e = blockIdx.x * 256 + threadIdx.x;
    if (e < EE) atomicAdd(&cnt[idx[EE + e]], 1);
}

// exclusive scan of cnt -> off (per-block), block totals -> bsum
__global__ void k_scanA(const int* __restrict__ cnt, int* __restrict__ off,
                        int* __restrict__ bsum) {
    __shared__ int sm[512];
    int i = blockIdx.x * 512 + threadIdx.x;
    int v = (i < NN) ? cnt[i] : 0;
    sm[threadIdx.x] = v;
    __syncthreads();
#pragma unroll
    for (int d = 1; d < 512; d <<= 1) {
        int t = (threadIdx.x >= d) ? sm[threadIdx.x - d] : 0;
        __syncthreads();
        sm[threadIdx.x] += t;
        __syncthreads();
    }
    if (i < NN) off[i] = sm[threadIdx.x] - v;  // exclusive within block
    if (threadIdx.x == 511) bsum[blockIdx.x] = sm[511];
}

__global__ void k_scanB(int* __restrict__ bsum) {
    __shared__ int sm[128];
    int tid = threadIdx.x;
    int v = (tid < NB_SCAN) ? bsum[tid] : 0;
    sm[tid] = v;
    __syncthreads();
#pragma unroll
    for (int d = 1; d < 128; d <<= 1) {
        int t = (tid >= d) ? sm[tid - d] : 0;
        __syncthreads();
        sm[tid] += t;
        __syncthreads();
    }
    if (tid < NB_SCAN) bsum[tid] = sm[tid] - v;  // exclusive
}

__global__ void k_scanC(int* __restrict__ off, const int* __restrict__ bsum,
                        int* __restrict__ cur) {
    int i = blockIdx.x * 256 + threadIdx.x;
    if (i < NN) {
        int o = off[i] + bsum[i >> 9];
        off[i] = o;
        cur[i] = o;
    }
}

__global__ void k_fill(const int* __restrict__ idx, const float* __restrict__ w,
                       int* __restrict__ cur, int* __restrict__ esrc,
                       float* __restrict__ ewgt) {
    int e = blockIdx.x * 256 + threadIdx.x;
    if (e >= EE) return;
    int c = idx[EE + e];
    int s = atomicAdd(&cur[c], 1);
    esrc[s] = idx[e];
    ewgt[s] = w[e];
}

__global__ void k_degdinv(const int* __restrict__ off, const int* __restrict__ cnt,
                          const float* __restrict__ ewgt, float* __restrict__ dinv) {
    int n = blockIdx.x * 256 + threadIdx.x;
    if (n >= NN) return;
    int s0 = off[n], c = cnt[n];
    float d = 1.f;  // self loop
    for (int q = 0; q < c; q++) d += ewgt[s0 + q];
    dinv[n] = rsqrtf(d);
}

// AX[b][n][t][f] = dinv[n]^2 * X[b][n][f][t] + sum_in nrm * X[b][src][f][t]
__global__ __launch_bounds__(256) void k_gather(const float* __restrict__ X,
                                                const float* __restrict__ dinv,
                                                const int* __restrict__ esrc,
                                                const float* __restrict__ ewgt,
                                                const int* __restrict__ off,
                                                const int* __restrict__ cnt,
                                                float* __restrict__ AX) {
    int tid = blockIdx.x * 256 + threadIdx.x;  // b*NN + n
    if (tid >= BB * NN) return;
    int b = tid / NN;
    int n = tid - b * NN;
    float di = dinv[n];
    const float* Xb = X + (size_t)b * NN * 24;

    float xf[24], acc[24];
    {
        const float4* xs = (const float4*)(Xb + (size_t)n * 24);
        float s = di * di;
#pragma unroll
        for (int q = 0; q < 6; q++) {
            float4 v = xs[q];
            xf[4 * q] = v.x; xf[4 * q + 1] = v.y; xf[4 * q + 2] = v.z; xf[4 * q + 3] = v.w;
        }
#pragma unroll
        for (int t = 0; t < TT; t++) {
            acc[2 * t] = s * xf[t];
            acc[2 * t + 1] = s * xf[12 + t];
        }
    }
    int s0 = off[n], c = cnt[n];
    for (int q = 0; q < c; q++) {
        int r = esrc[s0 + q];
        float nrm = dinv[r] * ewgt[s0 + q] * di;
        const float4* xr = (const float4*)(Xb + (size_t)r * 24);
#pragma unroll
        for (int p = 0; p < 6; p++) {
            float4 v = xr[p];
            xf[4 * p] = v.x; xf[4 * p + 1] = v.y; xf[4 * p + 2] = v.z; xf[4 * p + 3] = v.w;
        }
#pragma unroll
        for (int t = 0; t < TT; t++) {
            acc[2 * t] = fmaf(nrm, xf[t], acc[2 * t]);
            acc[2 * t + 1] = fmaf(nrm, xf[12 + t], acc[2 * t + 1]);
        }
    }
    float4* o = (float4*)(AX + (size_t)tid * 24);
#pragma unroll
    for (int q = 0; q < 6; q++)
        o[q] = make_float4(acc[4 * q], acc[4 * q + 1], acc[4 * q + 2], acc[4 * q + 3]);
}

// fold weights: per gate g at base g*1120: WF0[j]=sum_k W[0][k]Lw[k][j], WF1, cF, LB[k][j]=Lw[32+k][j]
__global__ void k_fold(const float* __restrict__ Wz, const float* __restrict__ bz,
                       const float* __restrict__ Lwz, const float* __restrict__ Lbz,
                       const float* __restrict__ Wr, const float* __restrict__ br,
                       const float* __restrict__ Lwr, const float* __restrict__ Lbr,
                       const float* __restrict__ Wh, const float* __restrict__ bh,
                       const float* __restrict__ Lwh, const float* __restrict__ Lbh,
                       const float* __restrict__ att, float* __restrict__ P) {
    int tid = threadIdx.x;
    if (tid < 96) {
        int g = tid >> 5, j = tid & 31;
        const float* W  = g == 0 ? Wz  : (g == 1 ? Wr  : Wh);
        const float* b  = g == 0 ? bz  : (g == 1 ? br  : bh);
        const float* Lw = g == 0 ? Lwz : (g == 1 ? Lwr : Lwh);
        const float* Lb = g == 0 ? Lbz : (g == 1 ? Lbr : Lbh);
        float* out = P + g * 1120;
        float w0 = 0.f, w1 = 0.f, c = 0.f;
        for (int k = 0; k < 32; k++) {
            float lw = Lw[k * 32 + j];
            w0 += W[k] * lw;
            w1 += W[32 + k] * lw;
            c  += b[k] * lw;
        }
        out[j] = w0;
        out[32 + j] = w1;
        out[64 + j] = c + Lb[j];
        for (int k = 0; k < 32; k++) out[96 + k * 32 + j] = Lw[(32 + k) * 32 + j];
    } else if (tid == 96) {
        float m = -1e30f;
        for (int t = 0; t < TT; t++) m = fmaxf(m, att[t]);
        float s = 0.f;
        float e[TT];
        for (int t = 0; t < TT; t++) { e[t] = __expf(att[t] - m); s += e[t]; }
        for (int t = 0; t < TT; t++) P[3360 + t] = e[t] / s;
    }
}

// j-per-lane recurrence: 1 wave per block, 2 nodes per wave (lane = grp*32 + j).
// Each lane holds its j-column of all folded weights in VGPRs.
// #pragma unroll 1 on the t-loop is CRITICAL: with full unroll (11x body,
// 176 float4 LDS reads) the scheduler explodes live ranges and the allocator
// falls back to 80 VGPRs + AGPR shuttling (R9-R14: VALUBusy 57%, ~285 insts/t
// vs ~150 useful). R7's only clean recurrence had unroll 1. Pins keep the
// weight loads non-rematerializable; (64,1) gives the full budget.
__global__ __launch_bounds__(64, 1) void k_recur(const float* __restrict__ AX,
                                                 const float* __restrict__ P,
                                                 float* __restrict__ out) {
    __shared__ __align__(16) float Hs[2][32];
    __shared__ __align__(16) float rHs[2][32];
    __shared__ __align__(16) float AXs[2][24];
    const int lane = threadIdx.x;   // 0..63
    const int j = lane & 31;
    const int grp = lane >> 5;

    // per-lane weight columns (loop-invariant, VGPR-resident)
    float LBz[32], LBr[32], LBh[32];
    float wz0 = P[j],        wz1 = P[32 + j],        cz = P[64 + j];
    float wr0 = P[1120 + j], wr1 = P[1120 + 32 + j], cr = P[1120 + 64 + j];
    float wh0 = P[2240 + j], wh1 = P[2240 + 32 + j], ch = P[2240 + 64 + j];
#pragma unroll
    for (int k = 0; k < 32; k++) {
        LBz[k] = P[96 + k * 32 + j];
        LBr[k] = P[1120 + 96 + k * 32 + j];
        LBh[k] = P[2240 + 96 + k * 32 + j];
    }
    // pin: forbid rematerialization of the weight loads
#pragma unroll
    for (int k = 0; k < 32; k++) {
        asm volatile("" : "+v"(LBz[k]), "+v"(LBr[k]), "+v"(LBh[k]));
    }
    asm volatile("" : "+v"(wz0), "+v"(wz1), "+v"(cz));
    asm volatile("" : "+v"(wr0), "+v"(wr1), "+v"(cr));
    asm volatile("" : "+v"(wh0), "+v"(wh1), "+v"(ch));

#pragma unroll 1
    for (int p = blockIdx.x; p < NPAIR; p += NBLK_REC) {
        int node = p * 2 + grp;
        if (j < 24) AXs[grp][j] = AX[(size_t)node * 24 + j];
        __syncthreads();

        // t = 0: H == 0 -> z/h init-only, rH == 0.
        float2 a = *(const float2*)&AXs[grp][0];
        float z = fsig(fmaf(a.x, wz0, fmaf(a.y, wz1, cz)));
        float th = ftanh(fmaf(a.x, wh0, fmaf(a.y, wh1, ch)));
        float H = (1.f - z) * th;
        float acc = P[3360] * H;
        Hs[grp][j] = H;
        __syncthreads();

#pragma unroll 1
        for (int t = 1; t < TT; t++) {
            a = *(const float2*)&AXs[grp][2 * t];
            // broadcast-read H (8 x b128 uniform per group)
            float hb[32];
#pragma unroll
            for (int i = 0; i < 8; i++) {
                float4 v = *(const float4*)&Hs[grp][4 * i];
                hb[4 * i] = v.x; hb[4 * i + 1] = v.y;
                hb[4 * i + 2] = v.z; hb[4 * i + 3] = v.w;
            }
            // r gate
            float r;
            {
                float s0 = 0.f, s1 = 0.f, s2 = 0.f, s3 = 0.f;
#pragma unroll
                for (int k = 0; k < 32; k += 4) {
                    s0 = fmaf(hb[k],     LBr[k],     s0);
                    s1 = fmaf(hb[k + 1], LBr[k + 1], s1);
                    s2 = fmaf(hb[k + 2], LBr[k + 2], s2);
                    s3 = fmaf(hb[k + 3], LBr[k + 3], s3);
                }
                r = fmaf(a.x, wr0, fmaf(a.y, wr1, cr)) + ((s0 + s1) + (s2 + s3));
            }
            rHs[grp][j] = fsig(r) * H;
            // z gate (uses hb; before barrier to overlap)
            {
                float s0 = 0.f, s1 = 0.f, s2 = 0.f, s3 = 0.f;
#pragma unroll
                for (int k = 0; k < 32; k += 4) {
                    s0 = fmaf(hb[k],     LBz[k],     s0);
                    s1 = fmaf(hb[k + 1], LBz[k + 1], s1);
                    s2 = fmaf(hb[k + 2], LBz[k + 2], s2);
                    s3 = fmaf(hb[k + 3], LBz[k + 3], s3);
                }
                z = fsig(fmaf(a.x, wz0, fmaf(a.y, wz1, cz)) + ((s0 + s1) + (s2 + s3)));
            }
            __syncthreads();
            // broadcast-read rH, h gate
            float rb[32];
#pragma unroll
            for (int i = 0; i < 8; i++) {
                float4 v = *(const float4*)&rHs[grp][4 * i];
                rb[4 * i] = v.x; rb[4 * i + 1] = v.y;
                rb[4 * i + 2] = v.z; rb[4 * i + 3] = v.w;
            }
            {
                float s0 = 0.f, s1 = 0.f, s2 = 0.f, s3 = 0.f;
#pragma unroll
                for (int k = 0; k < 32; k += 4) {
                    s0 = fmaf(rb[k],     LBh[k],     s0);
                    s1 = fmaf(rb[k + 1], LBh[k + 1], s1);
                    s2 = fmaf(rb[k + 2], LBh[k + 2], s2);
                    s3 = fmaf(rb[k + 3], LBh[k + 3], s3);
                }
                th = ftanh(fmaf(a.x, wh0, fmaf(a.y, wh1, ch)) + ((s0 + s1) + (s2 + s3)));
            }
            float Hn = fmaf(z, H - th, th);  // z*H + (1-z)*th
            H = Hn;
            acc = fmaf(P[3360 + t], Hn, acc);
            Hs[grp][j] = Hn;
            __syncthreads();
        }
        out[(size_t)node * 32 + j] = acc;
    }
}

extern "C" void kernel_launch(void* const* d_in, const int* in_sizes, int n_in,
                              void* d_out, int out_size, void* d_ws, size_t ws_size,
                              hipStream_t stream) {
    const float* X   = (const float*)d_in[0];
    const int*   idx = (const int*)d_in[1];
    const float* ew  = (const float*)d_in[2];
    const float* Wz  = (const float*)d_in[3];
    const float* bz  = (const float*)d_in[4];
    const float* Wr  = (const float*)d_in[5];
    const float* br  = (const float*)d_in[6];
    const float* Wh  = (const float*)d_in[7];
    const float* bh  = (const float*)d_in[8];
    const float* Lwz = (const float*)d_in[9];
    const float* Lbz = (const float*)d_in[10];
    const float* Lwr = (const float*)d_in[11];
    const float* Lbr = (const float*)d_in[12];
    const float* Lwh = (const float*)d_in[13];
    const float* Lbh = (const float*)d_in[14];
    const float* att = (const float*)d_in[15];

    float* ws   = (float*)d_ws;
    float* dinv = ws;
    float* AX   = ws + OFF_AX;
    float* P    = ws + OFF_P;
    int*   cnt  = (int*)ws + OFF_CNT;
    int*   off  = (int*)ws + OFF_OFF;
    int*   cur  = (int*)ws + OFF_CUR;
    int*   bsum = (int*)ws + OFF_BSUM;
    float* out  = (float*)d_out;
    int*   esrc = (int*)d_out;              // scratch inside d_out
    float* ewgt = (float*)d_out + EE;       // scratch inside d_out

    hipLaunchKernelGGL(k_zero, dim3((NN + 255) / 256), dim3(256), 0, stream, cnt);
    hipLaunchKernelGGL(k_count, dim3((EE + 255) / 256), dim3(256), 0, stream, idx, cnt);
    hipLaunchKernelGGL(k_scanA, dim3(NB_SCAN), dim3(512), 0, stream, cnt, off, bsum);
    hipLaunchKernelGGL(k_scanB, dim3(1), dim3(128), 0, stream, bsum);
    hipLaunchKernelGGL(k_scanC, dim3((NN + 255) / 256), dim3(256), 0, stream, off, bsum, cur);
    hipLaunchKernelGGL(k_fill, dim3((EE + 255) / 256), dim3(256), 0, stream, idx, ew, cur, esrc, ewgt);
    hipLaunchKernelGGL(k_degdinv, dim3((NN + 255) / 256), dim3(256), 0, stream, off, cnt, ewgt, dinv);
    hipLaunchKernelGGL(k_gather, dim3((BB * NN + 255) / 256), dim3(256), 0, stream,
                       X, dinv, esrc, ewgt, off, cnt, AX);
    hipLaunchKernelGGL(k_fold, dim3(1), dim3(128), 0, stream,
                       Wz, bz, Lwz, Lbz, Wr, br, Lwr, Lbr, Wh, bh, Lwh, Lbh, att, P);
    hipLaunchKernelGGL(k_recur, dim3(NBLK_REC), dim3(64), 0, stream, AX, P, out);
}

// Round 16
// 336.978 us; speedup vs baseline: 1.1923x; 1.1923x over previous
//
#include <hip/hip_runtime.h>

#define NN 50000
#define EE 800000
#define TT 12
#define BB 2

// ws layout (4B units):
//  [0, 50048)            dinv
//  [50048, 2450048)      AX[b][n][t][f]  (BB*NN*TT*2 floats)
//  [2450048, 2454144)    P folded params: per gate g at g*1120:
//          [0:32) WF0, [32:64) WF1, [64:96) cF, [96+32k+j) LB[k][j]
//        probs at [3360:3372)
//  [2454144, 2504192)    cnt (int)
//  [2504192, 2554240)    off (int)
//  [2554240, 2604288)    cur (int)
//  [2604288, 2604416)    bsum (int)
// CSR payload lives in d_out (fully overwritten by k_recur at the end):
//  d_out[0..800000)        esrc (int)
//  d_out[800000..1600000)  ewgt (float)
#define OFF_AX   50048
#define OFF_P    2450048
#define OFF_CNT  2454144
#define OFF_OFF  2504192
#define OFF_CUR  2554240
#define OFF_BSUM 2604288
#define NB_SCAN  98  // ceil(50000/512)
#define NPAIR    (BB * NN / 2)
#define NBLK_REC 6250   // 25000 pairs / 6250 = exactly 4 pairs per block;
                        // ~24 blocks/CU = 6 waves/SIMD (VGPR=80 allows 6).
                        // R11-R15 ran 2048 blocks = 2 waves/SIMD -> LDS-latency
                        // bound at VALUBusy 56%.

__device__ __forceinline__ float fsig(float x) {
    x = fminf(fmaxf(x, -30.f), 30.f);
    return __builtin_amdgcn_rcpf(1.f + __expf(-x));
}
__device__ __forceinline__ float ftanh(float x) {
    x = fminf(fmaxf(x, -15.f), 15.f);
    float e = __expf(-2.f * x);
    return (1.f - e) * __builtin_amdgcn_rcpf(1.f + e);
}

__global__ void k_zero(int* __restrict__ cnt) {
    int i = blockIdx.x * 256 + threadIdx.x;
    if (i < NN) cnt[i] = 0;
}

__global__ void k_count(const int* __restrict__ idx, int* __restrict__ cnt) {
    int e = blockIdx.x * 256 + threadIdx.x;
    if (e < EE) atomicAdd(&cnt[idx[EE + e]], 1);
}

// exclusive scan of cnt -> off (per-block), block totals -> bsum
__global__ void k_scanA(const int* __restrict__ cnt, int* __restrict__ off,
                        int* __restrict__ bsum) {
    __shared__ int sm[512];
    int i = blockIdx.x * 512 + threadIdx.x;
    int v = (i < NN) ? cnt[i] : 0;
    sm[threadIdx.x] = v;
    __syncthreads();
#pragma unroll
    for (int d = 1; d < 512; d <<= 1) {
        int t = (threadIdx.x >= d) ? sm[threadIdx.x - d] : 0;
        __syncthreads();
        sm[threadIdx.x] += t;
        __syncthreads();
    }
    if (i < NN) off[i] = sm[threadIdx.x] - v;  // exclusive within block
    if (threadIdx.x == 511) bsum[blockIdx.x] = sm[511];
}

__global__ void k_scanB(int* __restrict__ bsum) {
    __shared__ int sm[128];
    int tid = threadIdx.x;
    int v = (tid < NB_SCAN) ? bsum[tid] : 0;
    sm[tid] = v;
    __syncthreads();
#pragma unroll
    for (int d = 1; d < 128; d <<= 1) {
        int t = (tid >= d) ? sm[tid - d] : 0;
        __syncthreads();
        sm[tid] += t;
        __syncthreads();
    }
    if (tid < NB_SCAN) bsum[tid] = sm[tid] - v;  // exclusive
}

__global__ void k_scanC(int* __restrict__ off, const int* __restrict__ bsum,
                        int* __restrict__ cur) {
    int i = blockIdx.x * 256 + threadIdx.x;
    if (i < NN) {
        int o = off[i] + bsum[i >> 9];
        off[i] = o;
        cur[i] = o;
    }
}

__global__ void k_fill(const int* __restrict__ idx, const float* __restrict__ w,
                       int* __restrict__ cur, int* __restrict__ esrc,
                       float* __restrict__ ewgt) {
    int e = blockIdx.x * 256 + threadIdx.x;
    if (e >= EE) return;
    int c = idx[EE + e];
    int s = atomicAdd(&cur[c], 1);
    esrc[s] = idx[e];
    ewgt[s] = w[e];
}

__global__ void k_degdinv(const int* __restrict__ off, const int* __restrict__ cnt,
                          const float* __restrict__ ewgt, float* __restrict__ dinv) {
    int n = blockIdx.x * 256 + threadIdx.x;
    if (n >= NN) return;
    int s0 = off[n], c = cnt[n];
    float d = 1.f;  // self loop
    for (int q = 0; q < c; q++) d += ewgt[s0 + q];
    dinv[n] = rsqrtf(d);
}

// AX[b][n][t][f] = dinv[n]^2 * X[b][n][f][t] + sum_in nrm * X[b][src][f][t]
__global__ __launch_bounds__(256) void k_gather(const float* __restrict__ X,
                                                const float* __restrict__ dinv,
                                                const int* __restrict__ esrc,
                                                const float* __restrict__ ewgt,
                                                const int* __restrict__ off,
                                                const int* __restrict__ cnt,
                                                float* __restrict__ AX) {
    int tid = blockIdx.x * 256 + threadIdx.x;  // b*NN + n
    if (tid >= BB * NN) return;
    int b = tid / NN;
    int n = tid - b * NN;
    float di = dinv[n];
    const float* Xb = X + (size_t)b * NN * 24;

    float xf[24], acc[24];
    {
        const float4* xs = (const float4*)(Xb + (size_t)n * 24);
        float s = di * di;
#pragma unroll
        for (int q = 0; q < 6; q++) {
            float4 v = xs[q];
            xf[4 * q] = v.x; xf[4 * q + 1] = v.y; xf[4 * q + 2] = v.z; xf[4 * q + 3] = v.w;
        }
#pragma unroll
        for (int t = 0; t < TT; t++) {
            acc[2 * t] = s * xf[t];
            acc[2 * t + 1] = s * xf[12 + t];
        }
    }
    int s0 = off[n], c = cnt[n];
    for (int q = 0; q < c; q++) {
        int r = esrc[s0 + q];
        float nrm = dinv[r] * ewgt[s0 + q] * di;
        const float4* xr = (const float4*)(Xb + (size_t)r * 24);
#pragma unroll
        for (int p = 0; p < 6; p++) {
            float4 v = xr[p];
            xf[4 * p] = v.x; xf[4 * p + 1] = v.y; xf[4 * p + 2] = v.z; xf[4 * p + 3] = v.w;
        }
#pragma unroll
        for (int t = 0; t < TT; t++) {
            acc[2 * t] = fmaf(nrm, xf[t], acc[2 * t]);
            acc[2 * t + 1] = fmaf(nrm, xf[12 + t], acc[2 * t + 1]);
        }
    }
    float4* o = (float4*)(AX + (size_t)tid * 24);
#pragma unroll
    for (int q = 0; q < 6; q++)
        o[q] = make_float4(acc[4 * q], acc[4 * q + 1], acc[4 * q + 2], acc[4 * q + 3]);
}

// fold weights: per gate g at base g*1120: WF0[j]=sum_k W[0][k]Lw[k][j], WF1, cF, LB[k][j]=Lw[32+k][j]
__global__ void k_fold(const float* __restrict__ Wz, const float* __restrict__ bz,
                       const float* __restrict__ Lwz, const float* __restrict__ Lbz,
                       const float* __restrict__ Wr, const float* __restrict__ br,
                       const float* __restrict__ Lwr, const float* __restrict__ Lbr,
                       const float* __restrict__ Wh, const float* __restrict__ bh,
                       const float* __restrict__ Lwh, const float* __restrict__ Lbh,
                       const float* __restrict__ att, float* __restrict__ P) {
    int tid = threadIdx.x;
    if (tid < 96) {
        int g = tid >> 5, j = tid & 31;
        const float* W  = g == 0 ? Wz  : (g == 1 ? Wr  : Wh);
        const float* b  = g == 0 ? bz  : (g == 1 ? br  : bh);
        const float* Lw = g == 0 ? Lwz : (g == 1 ? Lwr : Lwh);
        const float* Lb = g == 0 ? Lbz : (g == 1 ? Lbr : Lbh);
        float* out = P + g * 1120;
        float w0 = 0.f, w1 = 0.f, c = 0.f;
        for (int k = 0; k < 32; k++) {
            float lw = Lw[k * 32 + j];
            w0 += W[k] * lw;
            w1 += W[32 + k] * lw;
            c  += b[k] * lw;
        }
        out[j] = w0;
        out[32 + j] = w1;
        out[64 + j] = c + Lb[j];
        for (int k = 0; k < 32; k++) out[96 + k * 32 + j] = Lw[(32 + k) * 32 + j];
    } else if (tid == 96) {
        float m = -1e30f;
        for (int t = 0; t < TT; t++) m = fmaxf(m, att[t]);
        float s = 0.f;
        float e[TT];
        for (int t = 0; t < TT; t++) { e[t] = __expf(att[t] - m); s += e[t]; }
        for (int t = 0; t < TT; t++) P[3360 + t] = e[t] / s;
    }
}

// j-per-lane recurrence: 1 wave per block, 2 nodes per wave (lane = grp*32 + j).
// Each lane holds its j-column of the folded weights; H/rH broadcast via LDS
// uniform float4 reads. 6250 blocks -> ~6 waves/SIMD hides the ds_read latency
// that capped 2048-block runs at VALUBusy 56% (R11/R14/R15 identical at 244us).
__global__ __launch_bounds__(64, 1) void k_recur(const float* __restrict__ AX,
                                                 const float* __restrict__ P,
                                                 float* __restrict__ out) {
    __shared__ __align__(16) float Hs[2][32];
    __shared__ __align__(16) float rHs[2][32];
    __shared__ __align__(16) float AXs[2][24];
    const int lane = threadIdx.x;   // 0..63
    const int j = lane & 31;
    const int grp = lane >> 5;

    // per-lane weight columns (loop-invariant)
    float LBz[32], LBr[32], LBh[32];
    float wz0 = P[j],        wz1 = P[32 + j],        cz = P[64 + j];
    float wr0 = P[1120 + j], wr1 = P[1120 + 32 + j], cr = P[1120 + 64 + j];
    float wh0 = P[2240 + j], wh1 = P[2240 + 32 + j], ch = P[2240 + 64 + j];
#pragma unroll
    for (int k = 0; k < 32; k++) {
        LBz[k] = P[96 + k * 32 + j];
        LBr[k] = P[1120 + 96 + k * 32 + j];
        LBh[k] = P[2240 + 96 + k * 32 + j];
    }

#pragma unroll 1
    for (int p = blockIdx.x; p < NPAIR; p += NBLK_REC) {
        int node = p * 2 + grp;
        if (j < 24) AXs[grp][j] = AX[(size_t)node * 24 + j];
        __syncthreads();

        // t = 0: H == 0 -> z/h init-only, rH == 0.
        float2 a = *(const float2*)&AXs[grp][0];
        float z = fsig(fmaf(a.x, wz0, fmaf(a.y, wz1, cz)));
        float th = ftanh(fmaf(a.x, wh0, fmaf(a.y, wh1, ch)));
        float H = (1.f - z) * th;
        float acc = P[3360] * H;
        Hs[grp][j] = H;
        __syncthreads();

#pragma unroll 1
        for (int t = 1; t < TT; t++) {
            a = *(const float2*)&AXs[grp][2 * t];
            // broadcast-read H (8 x b128 uniform per group)
            float hb[32];
#pragma unroll
            for (int i = 0; i < 8; i++) {
                float4 v = *(const float4*)&Hs[grp][4 * i];
                hb[4 * i] = v.x; hb[4 * i + 1] = v.y;
                hb[4 * i + 2] = v.z; hb[4 * i + 3] = v.w;
            }
            // r gate
            float r;
            {
                float s0 = 0.f, s1 = 0.f, s2 = 0.f, s3 = 0.f;
#pragma unroll
                for (int k = 0; k < 32; k += 4) {
                    s0 = fmaf(hb[k],     LBr[k],     s0);
                    s1 = fmaf(hb[k + 1], LBr[k + 1], s1);
                    s2 = fmaf(hb[k + 2], LBr[k + 2], s2);
                    s3 = fmaf(hb[k + 3], LBr[k + 3], s3);
                }
                r = fmaf(a.x, wr0, fmaf(a.y, wr1, cr)) + ((s0 + s1) + (s2 + s3));
            }
            rHs[grp][j] = fsig(r) * H;
            // z gate (uses hb; before barrier to overlap)
            {
                float s0 = 0.f, s1 = 0.f, s2 = 0.f, s3 = 0.f;
#pragma unroll
                for (int k = 0; k < 32; k += 4) {
                    s0 = fmaf(hb[k],     LBz[k],     s0);
                    s1 = fmaf(hb[k + 1], LBz[k + 1], s1);
                    s2 = fmaf(hb[k + 2], LBz[k + 2], s2);
                    s3 = fmaf(hb[k + 3], LBz[k + 3], s3);
                }
                z = fsig(fmaf(a.x, wz0, fmaf(a.y, wz1, cz)) + ((s0 + s1) + (s2 + s3)));
            }
            __syncthreads();
            // broadcast-read rH, h gate
            float rb[32];
#pragma unroll
            for (int i = 0; i < 8; i++) {
                float4 v = *(const float4*)&rHs[grp][4 * i];
                rb[4 * i] = v.x; rb[4 * i + 1] = v.y;
                rb[4 * i + 2] = v.z; rb[4 * i + 3] = v.w;
            }
            {
                float s0 = 0.f, s1 = 0.f, s2 = 0.f, s3 = 0.f;
#pragma unroll
                for (int k = 0; k < 32; k += 4) {
                    s0 = fmaf(rb[k],     LBh[k],     s0);
                    s1 = fmaf(rb[k + 1], LBh[k + 1], s1);
                    s2 = fmaf(rb[k + 2], LBh[k + 2], s2);
                    s3 = fmaf(rb[k + 3], LBh[k + 3], s3);
                }
                th = ftanh(fmaf(a.x, wh0, fmaf(a.y, wh1, ch)) + ((s0 + s1) + (s2 + s3)));
            }
            float Hn = fmaf(z, H - th, th);  // z*H + (1-z)*th
            H = Hn;
            acc = fmaf(P[3360 + t], Hn, acc);
            Hs[grp][j] = Hn;
            __syncthreads();
        }
        out[(size_t)node * 32 + j] = acc;
    }
}

extern "C" void kernel_launch(void* const* d_in, const int* in_sizes, int n_in,
                              void* d_out, int out_size, void* d_ws, size_t ws_size,
                              hipStream_t stream) {
    const float* X   = (const float*)d_in[0];
    const int*   idx = (const int*)d_in[1];
    const float* ew  = (const float*)d_in[2];
    const float* Wz  = (const float*)d_in[3];
    const float* bz  = (const float*)d_in[4];
    const float* Wr  = (const float*)d_in[5];
    const float* br  = (const float*)d_in[6];
    const float* Wh  = (const float*)d_in[7];
    const float* bh  = (const float*)d_in[8];
    const float* Lwz = (const float*)d_in[9];
    const float* Lbz = (const float*)d_in[10];
    const float* Lwr = (const float*)d_in[11];
    const float* Lbr = (const float*)d_in[12];
    const float* Lwh = (const float*)d_in[13];
    const float* Lbh = (const float*)d_in[14];
    const float* att = (const float*)d_in[15];

    float* ws   = (float*)d_ws;
    float* dinv = ws;
    float* AX   = ws + OFF_AX;
    float* P    = ws + OFF_P;
    int*   cnt  = (int*)ws + OFF_CNT;
    int*   off  = (int*)ws + OFF_OFF;
    int*   cur  = (int*)ws + OFF_CUR;
    int*   bsum = (int*)ws + OFF_BSUM;
    float* out  = (float*)d_out;
    int*   esrc = (int*)d_out;              // scratch inside d_out
    float* ewgt = (float*)d_out + EE;       // scratch inside d_out

    hipLaunchKernelGGL(k_zero, dim3((NN + 255) / 256), dim3(256), 0, stream, cnt);
    hipLaunchKernelGGL(k_count, dim3((EE + 255) / 256), dim3(256), 0, stream, idx, cnt);
    hipLaunchKernelGGL(k_scanA, dim3(NB_SCAN), dim3(512), 0, stream, cnt, off, bsum);
    hipLaunchKernelGGL(k_scanB, dim3(1), dim3(128), 0, stream, bsum);
    hipLaunchKernelGGL(k_scanC, dim3((NN + 255) / 256), dim3(256), 0, stream, off, bsum, cur);
    hipLaunchKernelGGL(k_fill, dim3((EE + 255) / 256), dim3(256), 0, stream, idx, ew, cur, esrc, ewgt);
    hipLaunchKernelGGL(k_degdinv, dim3((NN + 255) / 256), dim3(256), 0, stream, off, cnt, ewgt, dinv);
    hipLaunchKernelGGL(k_gather, dim3((BB * NN + 255) / 256), dim3(256), 0, stream,
                       X, dinv, esrc, ewgt, off, cnt, AX);
    hipLaunchKernelGGL(k_fold, dim3(1), dim3(128), 0, stream,
                       Wz, bz, Lwz, Lbz, Wr, br, Lwr, Lbr, Wh, bh, Lwh, Lbh, att, P);
    hipLaunchKernelGGL(k_recur, dim3(NBLK_REC), dim3(64), 0, stream, AX, P, out);
}

// Round 18
// 335.666 us; speedup vs baseline: 1.1970x; 1.0039x over previous
//
#include <hip/hip_runtime.h>

#define NN 50000
#define EE 800000
#define TT 12
#define BB 2

// ws layout (4B units):
//  [0, 50048)            dinv
//  [50048, 2450048)      AX[b][n][t][f]  (BB*NN*TT*2 floats)
//  [2450048, 2454144)    P folded params: per gate g at g*1120:
//          [0:32) WF0, [32:64) WF1, [64:96) cF, [96+32k+j) LB[k][j]
//        probs at [3360:3372)
//  [2454144, 2504192)    cnt (int)
//  [2504192, 2554240)    off (int)
//  [2554240, 2604288)    cur (int)
//  [2604288, 2604416)    bsum (int)
// CSR payload lives in d_out (fully overwritten by k_recur at the end):
//  d_out[0..800000)        esrc (int)
//  d_out[800000..1600000)  ewgt (float)
#define OFF_AX   50048
#define OFF_P    2450048
#define OFF_CNT  2454144
#define OFF_OFF  2504192
#define OFF_CUR  2554240
#define OFF_BSUM 2604288
#define NB_SCAN  98  // ceil(50000/512)
#define NPAIR    (BB * NN / 2)
#define NW       4      // waves per k_recur block
#define NBLK_REC 1563   // 1563 blocks x 4 waves = 6252 waves, ~4 pairs/wave.
                        // R16 evidence: single-wave workgroups cap at ~8/CU
                        // (Occupancy 25.5% despite 24 queued, VGPR=80 allows 6/SIMD)
                        // -> pack 4 waves/workgroup to get ~24 waves/CU.

__device__ __forceinline__ float fsig(float x) {
    x = fminf(fmaxf(x, -30.f), 30.f);
    return __builtin_amdgcn_rcpf(1.f + __expf(-x));
}
__device__ __forceinline__ float ftanh(float x) {
    x = fminf(fmaxf(x, -15.f), 15.f);
    float e = __expf(-2.f * x);
    return (1.f - e) * __builtin_amdgcn_rcpf(1.f + e);
}

__global__ void k_zero(int* __restrict__ cnt) {
    int i = blockIdx.x * 256 + threadIdx.x;
    if (i < NN) cnt[i] = 0;
}

__global__ void k_count(const int* __restrict__ idx, int* __restrict__ cnt) {
    int e = blockIdx.x * 256 + threadIdx.x;
    if (e < EE) atomicAdd(&cnt[idx[EE + e]], 1);
}

// exclusive scan of cnt -> off (per-block), block totals -> bsum
__global__ void k_scanA(const int* __restrict__ cnt, int* __restrict__ off,
                        int* __restrict__ bsum) {
    __shared__ int sm[512];
    int i = blockIdx.x * 512 + threadIdx.x;
    int v = (i < NN) ? cnt[i] : 0;
    sm[threadIdx.x] = v;
    __syncthreads();
#pragma unroll
    for (int d = 1; d < 512; d <<= 1) {
        int t = (threadIdx.x >= d) ? sm[threadIdx.x - d] : 0;
        __syncthreads();
        sm[threadIdx.x] += t;
        __syncthreads();
    }
    if (i < NN) off[i] = sm[threadIdx.x] - v;  // exclusive within block
    if (threadIdx.x == 511) bsum[blockIdx.x] = sm[511];
}

__global__ void k_scanB(int* __restrict__ bsum) {
    __shared__ int sm[128];
    int tid = threadIdx.x;
    int v = (tid < NB_SCAN) ? bsum[tid] : 0;
    sm[tid] = v;
    __syncthreads();
#pragma unroll
    for (int d = 1; d < 128; d <<= 1) {
        int t = (tid >= d) ? sm[tid - d] : 0;
        __syncthreads();
        sm[tid] += t;
        __syncthreads();
    }
    if (tid < NB_SCAN) bsum[tid] = sm[tid] - v;  // exclusive
}

__global__ void k_scanC(int* __restrict__ off, const int* __restrict__ bsum,
                        int* __restrict__ cur) {
    int i = blockIdx.x * 256 + threadIdx.x;
    if (i < NN) {
        int o = off[i] + bsum[i >> 9];
        off[i] = o;
        cur[i] = o;
    }
}

__global__ void k_fill(const int* __restrict__ idx, const float* __restrict__ w,
                       int* __restrict__ cur, int* __restrict__ esrc,
                       float* __restrict__ ewgt) {
    int e = blockIdx.x * 256 + threadIdx.x;
    if (e >= EE) return;
    int c = idx[EE + e];
    int s = atomicAdd(&cur[c], 1);
    esrc[s] = idx[e];
    ewgt[s] = w[e];
}

__global__ void k_degdinv(const int* __restrict__ off, const int* __restrict__ cnt,
                          const float* __restrict__ ewgt, float* __restrict__ dinv) {
    int n = blockIdx.x * 256 + threadIdx.x;
    if (n >= NN) return;
    int s0 = off[n], c = cnt[n];
    float d = 1.f;  // self loop
    for (int q = 0; q < c; q++) d += ewgt[s0 + q];
    dinv[n] = rsqrtf(d);
}

// AX[b][n][t][f] = dinv[n]^2 * X[b][n][f][t] + sum_in nrm * X[b][src][f][t]
__global__ __launch_bounds__(256) void k_gather(const float* __restrict__ X,
                                                const float* __restrict__ dinv,
                                                const int* __restrict__ esrc,
                                                const float* __restrict__ ewgt,
                                                const int* __restrict__ off,
                                                const int* __restrict__ cnt,
                                                float* __restrict__ AX) {
    int tid = blockIdx.x * 256 + threadIdx.x;  // b*NN + n
    if (tid >= BB * NN) return;
    int b = tid / NN;
    int n = tid - b * NN;
    float di = dinv[n];
    const float* Xb = X + (size_t)b * NN * 24;

    float xf[24], acc[24];
    {
        const float4* xs = (const float4*)(Xb + (size_t)n * 24);
        float s = di * di;
#pragma unroll
        for (int q = 0; q < 6; q++) {
            float4 v = xs[q];
            xf[4 * q] = v.x; xf[4 * q + 1] = v.y; xf[4 * q + 2] = v.z; xf[4 * q + 3] = v.w;
        }
#pragma unroll
        for (int t = 0; t < TT; t++) {
            acc[2 * t] = s * xf[t];
            acc[2 * t + 1] = s * xf[12 + t];
        }
    }
    int s0 = off[n], c = cnt[n];
    for (int q = 0; q < c; q++) {
        int r = esrc[s0 + q];
        float nrm = dinv[r] * ewgt[s0 + q] * di;
        const float4* xr = (const float4*)(Xb + (size_t)r * 24);
#pragma unroll
        for (int p = 0; p < 6; p++) {
            float4 v = xr[p];
            xf[4 * p] = v.x; xf[4 * p + 1] = v.y; xf[4 * p + 2] = v.z; xf[4 * p + 3] = v.w;
        }
#pragma unroll
        for (int t = 0; t < TT; t++) {
            acc[2 * t] = fmaf(nrm, xf[t], acc[2 * t]);
            acc[2 * t + 1] = fmaf(nrm, xf[12 + t], acc[2 * t + 1]);
        }
    }
    float4* o = (float4*)(AX + (size_t)tid * 24);
#pragma unroll
    for (int q = 0; q < 6; q++)
        o[q] = make_float4(acc[4 * q], acc[4 * q + 1], acc[4 * q + 2], acc[4 * q + 3]);
}

// fold weights: per gate g at base g*1120: WF0[j]=sum_k W[0][k]Lw[k][j], WF1, cF, LB[k][j]=Lw[32+k][j]
__global__ void k_fold(const float* __restrict__ Wz, const float* __restrict__ bz,
                       const float* __restrict__ Lwz, const float* __restrict__ Lbz,
                       const float* __restrict__ Wr, const float* __restrict__ br,
                       const float* __restrict__ Lwr, const float* __restrict__ Lbr,
                       const float* __restrict__ Wh, const float* __restrict__ bh,
                       const float* __restrict__ Lwh, const float* __restrict__ Lbh,
                       const float* __restrict__ att, float* __restrict__ P) {
    int tid = threadIdx.x;
    if (tid < 96) {
        int g = tid >> 5, j = tid & 31;
        const float* W  = g == 0 ? Wz  : (g == 1 ? Wr  : Wh);
        const float* b  = g == 0 ? bz  : (g == 1 ? br  : bh);
        const float* Lw = g == 0 ? Lwz : (g == 1 ? Lwr : Lwh);
        const float* Lb = g == 0 ? Lbz : (g == 1 ? Lbr : Lbh);
        float* out = P + g * 1120;
        float w0 = 0.f, w1 = 0.f, c = 0.f;
        for (int k = 0; k < 32; k++) {
            float lw = Lw[k * 32 + j];
            w0 += W[k] * lw;
            w1 += W[32 + k] * lw;
            c  += b[k] * lw;
        }
        out[j] = w0;
        out[32 + j] = w1;
        out[64 + j] = c + Lb[j];
        for (int k = 0; k < 32; k++) out[96 + k * 32 + j] = Lw[(32 + k) * 32 + j];
    } else if (tid == 96) {
        float m = -1e30f;
        for (int t = 0; t < TT; t++) m = fmaxf(m, att[t]);
        float s = 0.f;
        float e[TT];
        for (int t = 0; t < TT; t++) { e[t] = __expf(att[t] - m); s += e[t]; }
        for (int t = 0; t < TT; t++) P[3360 + t] = e[t] / s;
    }
}

// j-per-lane recurrence, 4 independent waves per 256-thread block.
// Wave w owns LDS regions Hs[w]/rHs[w]/AXs[w]; lanes exchange only within
// their own wave64 (lockstep) -> NO __syncthreads needed anywhere: the
// compiler orders the LDS write->read dependences with lgkmcnt.
// Multi-wave blocks dodge the ~8-workgroups/CU cap seen in R16 (single-wave
// blocks stuck at 25.5% occupancy = 2 waves/SIMD with VGPR=80 allowing 6).
__global__ __launch_bounds__(256) void k_recur(const float* __restrict__ AX,
                                               const float* __restrict__ P,
                                               float* __restrict__ out) {
    __shared__ __align__(16) float Hs[NW][2][32];
    __shared__ __align__(16) float rHs[NW][2][32];
    __shared__ __align__(16) float AXs[NW][2][24];
    const int lane = threadIdx.x & 63;
    const int w = threadIdx.x >> 6;       // wave id in block (wave-uniform)
    const int j = lane & 31;
    const int grp = lane >> 5;
    const int gwave = blockIdx.x * NW + w;

    // per-lane weight columns (loop-invariant)
    float LBz[32], LBr[32], LBh[32];
    float wz0 = P[j],        wz1 = P[32 + j],        cz = P[64 + j];
    float wr0 = P[1120 + j], wr1 = P[1120 + 32 + j], cr = P[1120 + 64 + j];
    float wh0 = P[2240 + j], wh1 = P[2240 + 32 + j], ch = P[2240 + 64 + j];
#pragma unroll
    for (int k = 0; k < 32; k++) {
        LBz[k] = P[96 + k * 32 + j];
        LBr[k] = P[1120 + 96 + k * 32 + j];
        LBh[k] = P[2240 + 96 + k * 32 + j];
    }

#pragma unroll 1
    for (int p = gwave; p < NPAIR; p += NBLK_REC * NW) {
        int node = p * 2 + grp;
        if (j < 24) AXs[w][grp][j] = AX[(size_t)node * 24 + j];
        // same-wave lockstep: lgkmcnt ordering suffices, no barrier

        // t = 0: H == 0 -> z/h init-only, rH == 0.
        float2 a = *(const float2*)&AXs[w][grp][0];
        float z = fsig(fmaf(a.x, wz0, fmaf(a.y, wz1, cz)));
        float th = ftanh(fmaf(a.x, wh0, fmaf(a.y, wh1, ch)));
        float H = (1.f - z) * th;
        float acc = P[3360] * H;
        Hs[w][grp][j] = H;

#pragma unroll 1
        for (int t = 1; t < TT; t++) {
            a = *(const float2*)&AXs[w][grp][2 * t];
            // broadcast-read H (8 x b128 uniform per group)
            float hb[32];
#pragma unroll
            for (int i = 0; i < 8; i++) {
                float4 v = *(const float4*)&Hs[w][grp][4 * i];
                hb[4 * i] = v.x; hb[4 * i + 1] = v.y;
                hb[4 * i + 2] = v.z; hb[4 * i + 3] = v.w;
            }
            // r gate
            float r;
            {
                float s0 = 0.f, s1 = 0.f, s2 = 0.f, s3 = 0.f;
#pragma unroll
                for (int k = 0; k < 32; k += 4) {
                    s0 = fmaf(hb[k],     LBr[k],     s0);
                    s1 = fmaf(hb[k + 1], LBr[k + 1], s1);
                    s2 = fmaf(hb[k + 2], LBr[k + 2], s2);
                    s3 = fmaf(hb[k + 3], LBr[k + 3], s3);
                }
                r = fmaf(a.x, wr0, fmaf(a.y, wr1, cr)) + ((s0 + s1) + (s2 + s3));
            }
            rHs[w][grp][j] = fsig(r) * H;
            // z gate (uses hb; overlaps the rHs write latency)
            {
                float s0 = 0.f, s1 = 0.f, s2 = 0.f, s3 = 0.f;
#pragma unroll
                for (int k = 0; k < 32; k += 4) {
                    s0 = fmaf(hb[k],     LBz[k],     s0);
                    s1 = fmaf(hb[k + 1], LBz[k + 1], s1);
                    s2 = fmaf(hb[k + 2], LBz[k + 2], s2);
                    s3 = fmaf(hb[k + 3], LBz[k + 3], s3);
                }
                z = fsig(fmaf(a.x, wz0, fmaf(a.y, wz1, cz)) + ((s0 + s1) + (s2 + s3)));
            }
            // broadcast-read rH, h gate
            float rb[32];
#pragma unroll
            for (int i = 0; i < 8; i++) {
                float4 v = *(const float4*)&rHs[w][grp][4 * i];
                rb[4 * i] = v.x; rb[4 * i + 1] = v.y;
                rb[4 * i + 2] = v.z; rb[4 * i + 3] = v.w;
            }
            {
                float s0 = 0.f, s1 = 0.f, s2 = 0.f, s3 = 0.f;
#pragma unroll
                for (int k = 0; k < 32; k += 4) {
                    s0 = fmaf(rb[k],     LBh[k],     s0);
                    s1 = fmaf(rb[k + 1], LBh[k + 1], s1);
                    s2 = fmaf(rb[k + 2], LBh[k + 2], s2);
                    s3 = fmaf(rb[k + 3], LBh[k + 3], s3);
                }
                th = ftanh(fmaf(a.x, wh0, fmaf(a.y, wh1, ch)) + ((s0 + s1) + (s2 + s3)));
            }
            float Hn = fmaf(z, H - th, th);  // z*H + (1-z)*th
            H = Hn;
            acc = fmaf(P[3360 + t], Hn, acc);
            Hs[w][grp][j] = Hn;
        }
        out[(size_t)node * 32 + j] = acc;
    }
}

extern "C" void kernel_launch(void* const* d_in, const int* in_sizes, int n_in,
                              void* d_out, int out_size, void* d_ws, size_t ws_size,
                              hipStream_t stream) {
    const float* X   = (const float*)d_in[0];
    const int*   idx = (const int*)d_in[1];
    const float* ew  = (const float*)d_in[2];
    const float* Wz  = (const float*)d_in[3];
    const float* bz  = (const float*)d_in[4];
    const float* Wr  = (const float*)d_in[5];
    const float* br  = (const float*)d_in[6];
    const float* Wh  = (const float*)d_in[7];
    const float* bh  = (const float*)d_in[8];
    const float* Lwz = (const float*)d_in[9];
    const float* Lbz = (const float*)d_in[10];
    const float* Lwr = (const float*)d_in[11];
    const float* Lbr = (const float*)d_in[12];
    const float* Lwh = (const float*)d_in[13];
    const float* Lbh = (const float*)d_in[14];
    const float* att = (const float*)d_in[15];

    float* ws   = (float*)d_ws;
    float* dinv = ws;
    float* AX   = ws + OFF_AX;
    float* P    = ws + OFF_P;
    int*   cnt  = (int*)ws + OFF_CNT;
    int*   off  = (int*)ws + OFF_OFF;
    int*   cur  = (int*)ws + OFF_CUR;
    int*   bsum = (int*)ws + OFF_BSUM;
    float* out  = (float*)d_out;
    int*   esrc = (int*)d_out;              // scratch inside d_out
    float* ewgt = (float*)d_out + EE;       // scratch inside d_out

    hipLaunchKernelGGL(k_zero, dim3((NN + 255) / 256), dim3(256), 0, stream, cnt);
    hipLaunchKernelGGL(k_count, dim3((EE + 255) / 256), dim3(256), 0, stream, idx, cnt);
    hipLaunchKernelGGL(k_scanA, dim3(NB_SCAN), dim3(512), 0, stream, cnt, off, bsum);
    hipLaunchKernelGGL(k_scanB, dim3(1), dim3(128), 0, stream, bsum);
    hipLaunchKernelGGL(k_scanC, dim3((NN + 255) / 256), dim3(256), 0, stream, off, bsum, cur);
    hipLaunchKernelGGL(k_fill, dim3((EE + 255) / 256), dim3(256), 0, stream, idx, ew, cur, esrc, ewgt);
    hipLaunchKernelGGL(k_degdinv, dim3((NN + 255) / 256), dim3(256), 0, stream, off, cnt, ewgt, dinv);
    hipLaunchKernelGGL(k_gather, dim3((BB * NN + 255) / 256), dim3(256), 0, stream,
                       X, dinv, esrc, ewgt, off, cnt, AX);
    hipLaunchKernelGGL(k_fold, dim3(1), dim3(128), 0, stream,
                       Wz, bz, Lwz, Lbz, Wr, br, Lwr, Lbr, Wh, bh, Lwh, Lbh, att, P);
    hipLaunchKernelGGL(k_recur, dim3(NBLK_REC), dim3(256), 0, stream, AX, P, out);
}